// Round 1
// baseline (572.830 us; speedup 1.0000x reference)
//
#include <hip/hip_runtime.h>
#include <cstdint>

typedef unsigned short u16;
typedef __attribute__((ext_vector_type(8))) __bf16 bf16x8;
typedef __attribute__((ext_vector_type(4))) float f32x4;

#define M_DIM 8192
#define N_DIM 4096
#define K_DIM 4096

// round-to-nearest-even f32 -> bf16 (inputs are Gaussian; no NaN handling needed)
__device__ __forceinline__ u16 f2bf(float f) {
    union { float f; uint32_t u; } v; v.f = f;
    uint32_t u = v.u;
    u += 0x7FFFu + ((u >> 16) & 1u);
    return (u16)(u >> 16);
}

// ---------------- x: f32 (M,K) -> bf16 (M,K) ----------------
__global__ __launch_bounds__(256) void cvt_x_kernel(const float* __restrict__ x,
                                                    u16* __restrict__ xb) {
    size_t i = ((size_t)blockIdx.x * 256 + threadIdx.x) * 8;
    const float4* p = (const float4*)(x + i);
    float4 v0 = p[0], v1 = p[1];
    uint32_t o0 = (uint32_t)f2bf(v0.x) | ((uint32_t)f2bf(v0.y) << 16);
    uint32_t o1 = (uint32_t)f2bf(v0.z) | ((uint32_t)f2bf(v0.w) << 16);
    uint32_t o2 = (uint32_t)f2bf(v1.x) | ((uint32_t)f2bf(v1.y) << 16);
    uint32_t o3 = (uint32_t)f2bf(v1.z) | ((uint32_t)f2bf(v1.w) << 16);
    uint4 o; o.x = o0; o.y = o1; o.z = o2; o.w = o3;
    *(uint4*)(xb + i) = o;
}

// ---------------- w: f32 (K,N) -> bf16 transposed (N,K) ----------------
__global__ __launch_bounds__(256) void cvt_wt_kernel(const float* __restrict__ w,
                                                     u16* __restrict__ wt) {
    __shared__ u16 lds[64 * 66];   // stride 66 ushorts = 33 words -> conflict-light
    const int t = threadIdx.x;
    const int k0 = blockIdx.x * 64;   // k tile origin
    const int n0 = blockIdx.y * 64;   // n tile origin
#pragma unroll
    for (int i = 0; i < 16; ++i) {
        int idx = i * 256 + t;
        int r = idx >> 6, c = idx & 63;       // r: local k, c: local n (coalesced read)
        lds[r * 66 + c] = f2bf(w[(size_t)(k0 + r) * N_DIM + n0 + c]);
    }
    __syncthreads();
#pragma unroll
    for (int i = 0; i < 8; ++i) {
        int idx = i * 256 + t;
        int rn = idx >> 5;                    // local n
        int ck = (idx & 31) * 2;              // local k (pair)
        uint32_t lo = lds[ck * 66 + rn];
        uint32_t hi = lds[(ck + 1) * 66 + rn];
        *(uint32_t*)&wt[(size_t)(n0 + rn) * K_DIM + k0 + ck] = lo | (hi << 16);
    }
}

// ---------------- GEMM: C = A(M,K) @ Bt(N,K)^T + bias, m97 structure ----------------
typedef const uint32_t __attribute__((address_space(1)))* gp_t;
typedef uint32_t __attribute__((address_space(3)))* lp_t;

__global__ __launch_bounds__(256) void gemm_kernel(const u16* __restrict__ A,
                                                   const u16* __restrict__ Bt,
                                                   const float* __restrict__ bias,
                                                   float* __restrict__ C) {
    __shared__ u16 As[128 * 32];   // 8 KB, [m][k] contiguous (global_load_lds order)
    __shared__ u16 Bs[128 * 32];   // 8 KB, [n][k]

    const int t    = threadIdx.x;
    const int lane = t & 63;
    const int l16  = lane & 15;
    const int quad = lane >> 4;
    const int wave = t >> 6;
    const int wm   = (wave >> 1) * 64;     // 2x2 waves of 64x64
    const int wn   = (wave & 1) * 64;
    const int bm   = blockIdx.y * 128;
    const int bn   = blockIdx.x * 128;

    f32x4 acc[4][4] = {};

    // staging: 512 chunks of 16B per tile; chunk = it*256 + t -> lds = base + lane*16 (wave-uniform)
    const int c0 = t, c1 = 256 + t;
    const int rA0 = c0 >> 2, kc0 = (c0 & 3) * 8;
    const int rA1 = c1 >> 2, kc1 = (c1 & 3) * 8;
    const u16* a0 = A  + (size_t)(bm + rA0) * K_DIM + kc0;
    const u16* a1 = A  + (size_t)(bm + rA1) * K_DIM + kc1;
    const u16* b0 = Bt + (size_t)(bn + rA0) * K_DIM + kc0;
    const u16* b1 = Bt + (size_t)(bn + rA1) * K_DIM + kc1;

    for (int k0 = 0; k0 < K_DIM; k0 += 32) {
        __syncthreads();  // previous compute done before overwrite
        __builtin_amdgcn_global_load_lds((gp_t)(a0 + k0), (lp_t)&As[c0 * 8], 16, 0, 0);
        __builtin_amdgcn_global_load_lds((gp_t)(a1 + k0), (lp_t)&As[c1 * 8], 16, 0, 0);
        __builtin_amdgcn_global_load_lds((gp_t)(b0 + k0), (lp_t)&Bs[c0 * 8], 16, 0, 0);
        __builtin_amdgcn_global_load_lds((gp_t)(b1 + k0), (lp_t)&Bs[c1 * 8], 16, 0, 0);
        __syncthreads();  // compiler emits vmcnt(0) drain here

        bf16x8 af[4], bf[4];
#pragma unroll
        for (int i = 0; i < 4; ++i) {
            af[i] = *(const bf16x8*)&As[(wm + i * 16 + l16) * 32 + quad * 8];
            bf[i] = *(const bf16x8*)&Bs[(wn + i * 16 + l16) * 32 + quad * 8];
        }
#pragma unroll
        for (int i = 0; i < 4; ++i)
#pragma unroll
            for (int j = 0; j < 4; ++j)
                acc[i][j] = __builtin_amdgcn_mfma_f32_16x16x32_bf16(af[i], bf[j], acc[i][j], 0, 0, 0);
    }

    // epilogue: C/D layout col=lane&15, row=quad*4+r (m89/m91-verified); fuse bias
#pragma unroll
    for (int j = 0; j < 4; ++j) {
        const int col = bn + wn + j * 16 + l16;
        const float bv = bias[col];
#pragma unroll
        for (int i = 0; i < 4; ++i) {
            const int row = bm + wm + i * 16 + quad * 4;
#pragma unroll
            for (int r = 0; r < 4; ++r)
                C[(size_t)(row + r) * N_DIM + col] = acc[i][j][r] + bv;
        }
    }
}

extern "C" void kernel_launch(void* const* d_in, const int* in_sizes, int n_in,
                              void* d_out, int out_size, void* d_ws, size_t ws_size,
                              hipStream_t stream) {
    const float* x = (const float*)d_in[0];   // (8192, 4096) f32
    const float* w = (const float*)d_in[1];   // (4096, 4096) f32
    const float* b = (const float*)d_in[2];   // (4096,)      f32
    float* out = (float*)d_out;               // (8192, 4096) f32

    // workspace: xb (M*K bf16, 64MB) + wt (N*K bf16, 32MB) = 96MB
    u16* xb = (u16*)d_ws;
    u16* wt = xb + (size_t)M_DIM * K_DIM;

    cvt_x_kernel<<<(M_DIM * (size_t)K_DIM) / (256 * 8), 256, 0, stream>>>(x, xb);
    cvt_wt_kernel<<<dim3(K_DIM / 64, N_DIM / 64), 256, 0, stream>>>(w, wt);
    gemm_kernel<<<dim3(N_DIM / 128, M_DIM / 128), 256, 0, stream>>>(xb, wt, b, out);
}

// Round 2
// 566.352 us; speedup vs baseline: 1.0114x; 1.0114x over previous
//
#include <hip/hip_runtime.h>
#include <cstdint>

typedef unsigned short u16;
typedef __attribute__((ext_vector_type(8))) __bf16 bf16x8;
typedef __attribute__((ext_vector_type(4))) float f32x4;

#define M_DIM 8192
#define N_DIM 4096
#define K_DIM 4096

#define CVT_X_BLOCKS 16384   // (M*K)/(256*8)
#define CVT_W_BLOCKS 4096    // (K/64)*(N/64)

// round-to-nearest-even f32 -> bf16 (inputs are Gaussian; no NaN handling needed)
__device__ __forceinline__ u16 f2bf(float f) {
    union { float f; uint32_t u; } v; v.f = f;
    uint32_t u = v.u;
    u += 0x7FFFu + ((u >> 16) & 1u);
    return (u16)(u >> 16);
}

// ---------------- merged converter: one launch for both inputs ----------------
// blocks [0, CVT_X_BLOCKS): x f32 (M,K) -> bf16 (M,K), streaming
// blocks [CVT_X_BLOCKS, +CVT_W_BLOCKS): w f32 (K,N) -> bf16 transposed (N,K), LDS tiled
__global__ __launch_bounds__(256) void cvt_kernel(const float* __restrict__ x,
                                                  const float* __restrict__ w,
                                                  u16* __restrict__ xb,
                                                  u16* __restrict__ wt) {
    const int t = threadIdx.x;
    if (blockIdx.x < CVT_X_BLOCKS) {
        size_t i = ((size_t)blockIdx.x * 256 + t) * 8;
        const float4* p = (const float4*)(x + i);
        float4 v0 = p[0], v1 = p[1];
        uint32_t o0 = (uint32_t)f2bf(v0.x) | ((uint32_t)f2bf(v0.y) << 16);
        uint32_t o1 = (uint32_t)f2bf(v0.z) | ((uint32_t)f2bf(v0.w) << 16);
        uint32_t o2 = (uint32_t)f2bf(v1.x) | ((uint32_t)f2bf(v1.y) << 16);
        uint32_t o3 = (uint32_t)f2bf(v1.z) | ((uint32_t)f2bf(v1.w) << 16);
        uint4 o; o.x = o0; o.y = o1; o.z = o2; o.w = o3;
        *(uint4*)(xb + i) = o;
    } else {
        __shared__ u16 lds[64 * 68];   // stride 68: keeps 8B-aligned b64 writes
        const int bid = blockIdx.x - CVT_X_BLOCKS;
        const int k0 = (bid & 63) * 64;   // k tile origin (K/64 = 64 tiles)
        const int n0 = (bid >> 6) * 64;   // n tile origin
        // stage 1: coalesced float4 reads of w rows, bf16 -> LDS (8B writes)
#pragma unroll
        for (int i = 0; i < 4; ++i) {
            int idx = i * 256 + t;
            int r = idx >> 4;            // local k row
            int c4 = (idx & 15) * 4;     // local n (group of 4)
            float4 v = *(const float4*)&w[(size_t)(k0 + r) * N_DIM + n0 + c4];
            uint2 o;
            o.x = (uint32_t)f2bf(v.x) | ((uint32_t)f2bf(v.y) << 16);
            o.y = (uint32_t)f2bf(v.z) | ((uint32_t)f2bf(v.w) << 16);
            *(uint2*)&lds[r * 68 + c4] = o;
        }
        __syncthreads();
        // stage 2: transpose out of LDS, 8B global writes along k
#pragma unroll
        for (int i = 0; i < 4; ++i) {
            int idx = i * 256 + t;
            int rn  = idx >> 4;          // local n
            int ck  = (idx & 15) * 4;    // local k (group of 4)
            uint2 o;
            o.x = (uint32_t)lds[(ck + 0) * 68 + rn] | ((uint32_t)lds[(ck + 1) * 68 + rn] << 16);
            o.y = (uint32_t)lds[(ck + 2) * 68 + rn] | ((uint32_t)lds[(ck + 3) * 68 + rn] << 16);
            *(uint2*)&wt[(size_t)(n0 + rn) * K_DIM + k0 + ck] = o;
        }
    }
}

// ---------------- GEMM: C = A(M,K) @ Bt(N,K)^T + bias, m97 structure ----------------
// LDS k-chunk XOR swizzle: logical chunk q of row r lives at slot q ^ ((r>>1)&3).
// Read bank = 16*(row&1) + 4*(quad^((row>>1)&3)) -> bijection on l16&7 -> 2-way, free.
typedef const uint32_t __attribute__((address_space(1)))* gp_t;
typedef uint32_t __attribute__((address_space(3)))* lp_t;

__global__ __launch_bounds__(256) void gemm_kernel(const u16* __restrict__ A,
                                                   const u16* __restrict__ Bt,
                                                   const float* __restrict__ bias,
                                                   float* __restrict__ C) {
    __shared__ u16 As[128 * 32];   // 8 KB, [m][k-slot] (global_load_lds contiguous order)
    __shared__ u16 Bs[128 * 32];   // 8 KB, [n][k-slot]

    const int t    = threadIdx.x;
    const int lane = t & 63;
    const int l16  = lane & 15;
    const int quad = lane >> 4;
    const int wave = t >> 6;
    const int wm   = (wave >> 1) * 64;     // 2x2 waves of 64x64
    const int wn   = (wave & 1) * 64;
    const int bm   = blockIdx.y * 128;
    const int bn   = blockIdx.x * 128;

    f32x4 acc[4][4] = {};

    // staging: chunk c = {t, 256+t}; row = c>>2, slot = c&3; fetch global k-chunk (slot ^ ((row>>1)&3))
    const int c0 = t, c1 = 256 + t;
    const int rA0 = c0 >> 2, rA1 = c1 >> 2;
    const int sw  = ((rA0 >> 1) & 3);                 // same for c1 (row1 = row0 + 64)
    const int kc  = ((c0 & 3) ^ sw) * 8;
    const u16* a0 = A  + (size_t)(bm + rA0) * K_DIM + kc;
    const u16* a1 = A  + (size_t)(bm + rA1) * K_DIM + kc;
    const u16* b0 = Bt + (size_t)(bn + rA0) * K_DIM + kc;
    const u16* b1 = Bt + (size_t)(bn + rA1) * K_DIM + kc;

    // read-side swizzled slot offset (uniform over i since wm/wn, i*16 are mult of 16)
    const int sw8 = (quad ^ ((l16 >> 1) & 3)) * 8;

    for (int k0 = 0; k0 < K_DIM; k0 += 32) {
        __syncthreads();  // previous compute done before overwrite
        __builtin_amdgcn_global_load_lds((gp_t)(a0 + k0), (lp_t)&As[c0 * 8], 16, 0, 0);
        __builtin_amdgcn_global_load_lds((gp_t)(a1 + k0), (lp_t)&As[c1 * 8], 16, 0, 0);
        __builtin_amdgcn_global_load_lds((gp_t)(b0 + k0), (lp_t)&Bs[c0 * 8], 16, 0, 0);
        __builtin_amdgcn_global_load_lds((gp_t)(b1 + k0), (lp_t)&Bs[c1 * 8], 16, 0, 0);
        __syncthreads();  // compiler emits vmcnt(0) drain here

        bf16x8 af[4], bf[4];
#pragma unroll
        for (int i = 0; i < 4; ++i) {
            af[i] = *(const bf16x8*)&As[(wm + i * 16 + l16) * 32 + sw8];
            bf[i] = *(const bf16x8*)&Bs[(wn + i * 16 + l16) * 32 + sw8];
        }
#pragma unroll
        for (int i = 0; i < 4; ++i)
#pragma unroll
            for (int j = 0; j < 4; ++j)
                acc[i][j] = __builtin_amdgcn_mfma_f32_16x16x32_bf16(af[i], bf[j], acc[i][j], 0, 0, 0);
    }

    // epilogue: C/D layout col=lane&15, row=quad*4+r (m89/m91-verified); fuse bias
#pragma unroll
    for (int j = 0; j < 4; ++j) {
        const int col = bn + wn + j * 16 + l16;
        const float bv = bias[col];
#pragma unroll
        for (int i = 0; i < 4; ++i) {
            const int row = bm + wm + i * 16 + quad * 4;
#pragma unroll
            for (int r = 0; r < 4; ++r)
                C[(size_t)(row + r) * N_DIM + col] = acc[i][j][r] + bv;
        }
    }
}

extern "C" void kernel_launch(void* const* d_in, const int* in_sizes, int n_in,
                              void* d_out, int out_size, void* d_ws, size_t ws_size,
                              hipStream_t stream) {
    const float* x = (const float*)d_in[0];   // (8192, 4096) f32
    const float* w = (const float*)d_in[1];   // (4096, 4096) f32
    const float* b = (const float*)d_in[2];   // (4096,)      f32
    float* out = (float*)d_out;               // (8192, 4096) f32

    // workspace: xb (M*K bf16, 64MB) + wt (N*K bf16, 32MB) = 96MB
    u16* xb = (u16*)d_ws;
    u16* wt = xb + (size_t)M_DIM * K_DIM;

    cvt_kernel<<<CVT_X_BLOCKS + CVT_W_BLOCKS, 256, 0, stream>>>(x, w, xb, wt);
    gemm_kernel<<<dim3(N_DIM / 128, M_DIM / 128), 256, 0, stream>>>(xb, wt, b, out);
}